// Round 1
// 704.340 us; speedup vs baseline: 1.0160x; 1.0160x over previous
//
#include <hip/hip_runtime.h>
#include <math.h>

namespace {
constexpr int   Cc   = 256;
constexpr int   HWc  = 256 * 256;          // 65536 pixels per image
constexpr int   Bc   = 8;
constexpr int   IMGS = Bc * HWc * 3;       // imgs block, then data block
constexpr float PI_F = 3.14159265358979f;

constexpr int   PX   = 2;                  // pixels per thread
constexpr int   BLK  = 256;                // threads per block
constexpr int   PPB  = PX * BLK;           // 512 pixels per block
constexpr int   BPI  = HWc / PPB;          // 128 blocks per image

__device__ __forceinline__ float sigm(float x) { return 1.0f / (1.0f + expf(-x)); }

__device__ __forceinline__ float comp2(const float2& v, int p) {
    return p == 0 ? v.x : v.y;
}
} // namespace

// One thread = 2 consecutive pixels. Block = 256 threads = 512 pixels.
// 128 blocks per batch image, 1024 blocks total -> 4 blocks/CU = 16 waves/CU.
extern "C" __global__ __launch_bounds__(BLK, 4)
void brdf_fwd(const float* __restrict__ feats,
              const float* __restrict__ wi,
              const float* __restrict__ wo,
              const float* __restrict__ wn,
              const float* __restrict__ wa,
              const float* __restrict__ wr,
              const float* __restrict__ wf,
              float* __restrict__ out)
{
    // Weights staged in LDS, stride 12 floats (48 B -> float4-aligned per c).
    // Hot-loop reads are wave-uniform (broadcast, conflict-free).
    __shared__ float wlds[Cc * 12];
    const int tid = threadIdx.x;
    {
        const int c = tid;  // blockDim.x == Cc == 256
        float v0 = wn[c], v1 = wn[Cc + c], v2 = wn[2 * Cc + c];
        float v3 = wa[c], v4 = wa[Cc + c], v5 = wa[2 * Cc + c];
        float v6 = wr[c];
        float v7 = wf[c], v8 = wf[Cc + c], v9 = wf[2 * Cc + c];
        float* p = &wlds[c * 12];
        p[0] = v0; p[1] = v1; p[2] = v2; p[3] = v3; p[4] = v4; p[5] = v5;
        p[6] = v6; p[7] = v7; p[8] = v8; p[9] = v9; p[10] = 0.f; p[11] = 0.f;
    }
    __syncthreads();

    const int b    = blockIdx.x / BPI;
    const int pix0 = ((blockIdx.x % BPI) * BLK + tid) * PX;  // first of 2 pixels
    const int gpix = b * HWc + pix0;

    // Issue wi/wo loads EARLY so they overlap the feats stream.
    // gpix is even -> gpix*3 floats is 8-byte aligned: 3x float2 each.
    const float2* wip = reinterpret_cast<const float2*>(wi + (size_t)gpix * 3);
    const float2* wop = reinterpret_cast<const float2*>(wo + (size_t)gpix * 3);
    const float2 wiA = wip[0], wiB = wip[1], wiC = wip[2];
    const float2 woA = wop[0], woB = wop[1], woC = wop[2];

    const float* fbase = feats + (size_t)b * Cc * HWc + pix0;

    // acc[o] = float2 over the 2 pixels; o: 0-2 normal, 3-5 albedo, 6 rough, 7-9 fresnel
    float2 acc[10];
#pragma unroll
    for (int o = 0; o < 10; ++o) acc[o] = make_float2(0.f, 0.f);

#define FMA2(A, S)                          \
    {                                       \
        (A).x = fmaf(f.x, (S), (A).x);      \
        (A).y = fmaf(f.y, (S), (A).y);      \
    }

#pragma unroll 8
    for (int c = 0; c < Cc; ++c) {
        const float2 f  = *reinterpret_cast<const float2*>(fbase + (size_t)c * HWc);
        const float4 w0 = *reinterpret_cast<const float4*>(&wlds[c * 12 + 0]);
        const float4 w1 = *reinterpret_cast<const float4*>(&wlds[c * 12 + 4]);
        const float2 w2 = *reinterpret_cast<const float2*>(&wlds[c * 12 + 8]);
        FMA2(acc[0], w0.x); FMA2(acc[1], w0.y); FMA2(acc[2], w0.z);
        FMA2(acc[3], w0.w); FMA2(acc[4], w1.x); FMA2(acc[5], w1.y);
        FMA2(acc[6], w1.z); FMA2(acc[7], w1.w); FMA2(acc[8], w2.x);
        FMA2(acc[9], w2.y);
    }
#undef FMA2

    const float wiv[6] = {wiA.x, wiA.y, wiB.x, wiB.y, wiC.x, wiC.y};
    const float wov[6] = {woA.x, woA.y, woB.x, woB.y, woC.x, woC.y};

    float imgsv[6];
    float datav[24];

#pragma unroll
    for (int p = 0; p < PX; ++p) {
        // ---- activations ----
        float nx = tanhf(comp2(acc[0], p));
        float ny = tanhf(comp2(acc[1], p));
        float nz = tanhf(comp2(acc[2], p));
        {
            float nlen = sqrtf(nx * nx + ny * ny + nz * nz);
            float ninv = 1.0f / fmaxf(nlen, 1e-12f);
            nx *= ninv; ny *= ninv; nz *= ninv;
        }
        float a0  = sigm(comp2(acc[3], p));
        float a1  = sigm(comp2(acc[4], p));
        float a2c = sigm(comp2(acc[5], p));
        float rg  = fminf(fmaxf(sigm(comp2(acc[6], p)), 0.001f), 1.0f);
        float f0x = sigm(comp2(acc[7], p));
        float f0y = sigm(comp2(acc[8], p));
        float f0z = sigm(comp2(acc[9], p));

        // ---- data output (B,H,W,12): n, albedo, rough x3, fresnel ----
        float* dv = &datav[p * 12];
        dv[0] = nx;  dv[1] = ny;  dv[2] = nz;
        dv[3] = a0;  dv[4] = a1;  dv[5] = a2c;
        dv[6] = rg;  dv[7] = rg;  dv[8] = rg;
        dv[9] = f0x; dv[10] = f0y; dv[11] = f0z;

        // ---- GGX render ----
        float lx = wiv[p * 3 + 0], ly = wiv[p * 3 + 1], lz = wiv[p * 3 + 2];
        float vx = wov[p * 3 + 0], vy = wov[p * 3 + 1], vz = wov[p * 3 + 2];
        {
            float li = 1.0f / fmaxf(sqrtf(lx * lx + ly * ly + lz * lz), 1e-12f);
            lx *= li; ly *= li; lz *= li;
            float vi = 1.0f / fmaxf(sqrtf(vx * vx + vy * vy + vz * vz), 1e-12f);
            vx *= vi; vy *= vi; vz *= vi;
        }
        float hx = lx + vx, hy = ly + vy, hz = lz + vz;
        {
            float hi = 1.0f / fmaxf(sqrtf(hx * hx + hy * hy + hz * hz), 1e-12f);
            hx *= hi; hy *= hi; hz *= hi;
        }
        float NdotH = fmaxf(nx * hx + ny * hy + nz * hz, 1e-8f);
        float NdotL = fmaxf(nx * lx + ny * ly + nz * lz, 1e-8f);
        float NdotV = fmaxf(nx * vx + ny * vy + nz * vz, 1e-8f);
        float VdotH = fmaxf(vx * hx + vy * hy + vz * hz, 1e-8f);

        float alpha = rg * rg;
        float a2g   = alpha * alpha;
        float den   = NdotH * NdotH * (a2g - 1.0f) + 1.0f;
        float D     = a2g / (PI_F * den * den);
        float e     = exp2f((-5.55473f * VdotH - 6.98316f) * VdotH);
        float k     = alpha * 0.5f;
        float G     = (1.0f / (NdotL * (1.0f - k) + k)) * (1.0f / (NdotV * (1.0f - k) + k));
        float sDG   = 0.25f * D * G;

        float* iv = &imgsv[p * 3];
        {
            float F0[3] = {f0x, f0y, f0z};
            float AL[3] = {a0, a1, a2c};
#pragma unroll
            for (int ch = 0; ch < 3; ++ch) {
                float F    = F0[ch] + (1.0f - F0[ch]) * e;
                float spec = sDG * F;
                float diff = AL[ch] * (1.0f - F0[ch]) * (1.0f / PI_F);
                iv[ch] = fmaxf((diff + spec) * NdotL, 0.0f);
            }
        }
    }

    // ---- stores ----
    // imgs: 6 floats per thread, 8-byte aligned -> 3x float2.
    float2* ip = reinterpret_cast<float2*>(out + (size_t)gpix * 3);
    ip[0] = make_float2(imgsv[0], imgsv[1]);
    ip[1] = make_float2(imgsv[2], imgsv[3]);
    ip[2] = make_float2(imgsv[4], imgsv[5]);

    // data: 24 floats per thread, 16-byte aligned -> 6x float4.
    float4* dp = reinterpret_cast<float4*>(out + (size_t)IMGS + (size_t)gpix * 12);
#pragma unroll
    for (int q = 0; q < 6; ++q)
        dp[q] = make_float4(datav[q * 4 + 0], datav[q * 4 + 1],
                            datav[q * 4 + 2], datav[q * 4 + 3]);
}

extern "C" void kernel_launch(void* const* d_in, const int* in_sizes, int n_in,
                              void* d_out, int out_size, void* d_ws, size_t ws_size,
                              hipStream_t stream) {
    const float* feats = (const float*)d_in[0];
    const float* wi    = (const float*)d_in[1];
    const float* wo    = (const float*)d_in[2];
    const float* wn    = (const float*)d_in[3];
    const float* wa    = (const float*)d_in[4];
    const float* wr    = (const float*)d_in[5];
    const float* wf    = (const float*)d_in[6];
    float* out = (float*)d_out;

    dim3 grid(Bc * BPI);   // 1024 blocks
    dim3 block(BLK);
    hipLaunchKernelGGL(brdf_fwd, grid, block, 0, stream,
                       feats, wi, wo, wn, wa, wr, wf, out);
}

// Round 2
// 703.859 us; speedup vs baseline: 1.0167x; 1.0007x over previous
//
#include <hip/hip_runtime.h>
#include <math.h>

namespace {
constexpr int   Cc   = 256;
constexpr int   HWc  = 256 * 256;          // 65536 pixels per image
constexpr int   Bc   = 8;
constexpr int   IMGS = Bc * HWc * 3;       // imgs block, then data block
constexpr float PI_F = 3.14159265358979f;

constexpr int   PX   = 2;                  // pixels per thread
constexpr int   BLK  = 256;                // threads per block
constexpr int   PPB  = PX * BLK;           // 512 pixels per block
constexpr int   BPI  = HWc / PPB;          // 128 blocks per image

__device__ __forceinline__ float sigm(float x) { return 1.0f / (1.0f + expf(-x)); }

__device__ __forceinline__ float comp2(const float2& v, int p) {
    return p == 0 ? v.x : v.y;
}
} // namespace

// One thread = 2 consecutive pixels. Block = 256 threads = 512 pixels.
// 128 blocks per image, 1024 blocks total.
// __launch_bounds__(256,5): 5 waves/EU -> 5 blocks/CU = 20 waves/CU,
// VGPR cap 102 (est. live ~80, no spill), LDS 12KB x 5 = 60KB <= 160KB.
// Goal: ~40KB of in-flight feats loads per CU (> 22KB needed to hide
// ~900cy HBM latency at 24.6 B/cy/CU).
extern "C" __global__ __launch_bounds__(BLK, 5)
void brdf_fwd(const float* __restrict__ feats,
              const float* __restrict__ wi,
              const float* __restrict__ wo,
              const float* __restrict__ wn,
              const float* __restrict__ wa,
              const float* __restrict__ wr,
              const float* __restrict__ wf,
              float* __restrict__ out)
{
    // Weights staged in LDS, stride 12 floats (48 B -> float4-aligned per c).
    // Hot-loop reads are wave-uniform (broadcast, conflict-free).
    __shared__ float wlds[Cc * 12];
    const int tid = threadIdx.x;
    {
        const int c = tid;  // blockDim.x == Cc == 256
        float v0 = wn[c], v1 = wn[Cc + c], v2 = wn[2 * Cc + c];
        float v3 = wa[c], v4 = wa[Cc + c], v5 = wa[2 * Cc + c];
        float v6 = wr[c];
        float v7 = wf[c], v8 = wf[Cc + c], v9 = wf[2 * Cc + c];
        float* p = &wlds[c * 12];
        p[0] = v0; p[1] = v1; p[2] = v2; p[3] = v3; p[4] = v4; p[5] = v5;
        p[6] = v6; p[7] = v7; p[8] = v8; p[9] = v9; p[10] = 0.f; p[11] = 0.f;
    }
    __syncthreads();

    const int b    = blockIdx.x / BPI;
    const int pix0 = ((blockIdx.x % BPI) * BLK + tid) * PX;  // first of 2 pixels
    const int gpix = b * HWc + pix0;

    // Issue wi/wo loads EARLY so they overlap the feats stream.
    // gpix is even -> gpix*3 floats is 8-byte aligned: 3x float2 each.
    const float2* wip = reinterpret_cast<const float2*>(wi + (size_t)gpix * 3);
    const float2* wop = reinterpret_cast<const float2*>(wo + (size_t)gpix * 3);
    const float2 wiA = wip[0], wiB = wip[1], wiC = wip[2];
    const float2 woA = wop[0], woB = wop[1], woC = wop[2];

    const float* fbase = feats + (size_t)b * Cc * HWc + pix0;

    // acc[o] = float2 over the 2 pixels; o: 0-2 normal, 3-5 albedo, 6 rough, 7-9 fresnel
    float2 acc[10];
#pragma unroll
    for (int o = 0; o < 10; ++o) acc[o] = make_float2(0.f, 0.f);

#define FMA2(A, S)                          \
    {                                       \
        (A).x = fmaf(f.x, (S), (A).x);      \
        (A).y = fmaf(f.y, (S), (A).y);      \
    }

#pragma unroll 8
    for (int c = 0; c < Cc; ++c) {
        const float2 f  = *reinterpret_cast<const float2*>(fbase + (size_t)c * HWc);
        const float4 w0 = *reinterpret_cast<const float4*>(&wlds[c * 12 + 0]);
        const float4 w1 = *reinterpret_cast<const float4*>(&wlds[c * 12 + 4]);
        const float2 w2 = *reinterpret_cast<const float2*>(&wlds[c * 12 + 8]);
        FMA2(acc[0], w0.x); FMA2(acc[1], w0.y); FMA2(acc[2], w0.z);
        FMA2(acc[3], w0.w); FMA2(acc[4], w1.x); FMA2(acc[5], w1.y);
        FMA2(acc[6], w1.z); FMA2(acc[7], w1.w); FMA2(acc[8], w2.x);
        FMA2(acc[9], w2.y);
    }
#undef FMA2

    const float wiv[6] = {wiA.x, wiA.y, wiB.x, wiB.y, wiC.x, wiC.y};
    const float wov[6] = {woA.x, woA.y, woB.x, woB.y, woC.x, woC.y};

    float imgsv[6];
    float datav[24];

#pragma unroll
    for (int p = 0; p < PX; ++p) {
        // ---- activations ----
        float nx = tanhf(comp2(acc[0], p));
        float ny = tanhf(comp2(acc[1], p));
        float nz = tanhf(comp2(acc[2], p));
        {
            float nlen = sqrtf(nx * nx + ny * ny + nz * nz);
            float ninv = 1.0f / fmaxf(nlen, 1e-12f);
            nx *= ninv; ny *= ninv; nz *= ninv;
        }
        float a0  = sigm(comp2(acc[3], p));
        float a1  = sigm(comp2(acc[4], p));
        float a2c = sigm(comp2(acc[5], p));
        float rg  = fminf(fmaxf(sigm(comp2(acc[6], p)), 0.001f), 1.0f);
        float f0x = sigm(comp2(acc[7], p));
        float f0y = sigm(comp2(acc[8], p));
        float f0z = sigm(comp2(acc[9], p));

        // ---- data output (B,H,W,12): n, albedo, rough x3, fresnel ----
        float* dv = &datav[p * 12];
        dv[0] = nx;  dv[1] = ny;  dv[2] = nz;
        dv[3] = a0;  dv[4] = a1;  dv[5] = a2c;
        dv[6] = rg;  dv[7] = rg;  dv[8] = rg;
        dv[9] = f0x; dv[10] = f0y; dv[11] = f0z;

        // ---- GGX render ----
        float lx = wiv[p * 3 + 0], ly = wiv[p * 3 + 1], lz = wiv[p * 3 + 2];
        float vx = wov[p * 3 + 0], vy = wov[p * 3 + 1], vz = wov[p * 3 + 2];
        {
            float li = 1.0f / fmaxf(sqrtf(lx * lx + ly * ly + lz * lz), 1e-12f);
            lx *= li; ly *= li; lz *= li;
            float vi = 1.0f / fmaxf(sqrtf(vx * vx + vy * vy + vz * vz), 1e-12f);
            vx *= vi; vy *= vi; vz *= vi;
        }
        float hx = lx + vx, hy = ly + vy, hz = lz + vz;
        {
            float hi = 1.0f / fmaxf(sqrtf(hx * hx + hy * hy + hz * hz), 1e-12f);
            hx *= hi; hy *= hi; hz *= hi;
        }
        float NdotH = fmaxf(nx * hx + ny * hy + nz * hz, 1e-8f);
        float NdotL = fmaxf(nx * lx + ny * ly + nz * lz, 1e-8f);
        float NdotV = fmaxf(nx * vx + ny * vy + nz * vz, 1e-8f);
        float VdotH = fmaxf(vx * hx + vy * hy + vz * hz, 1e-8f);

        float alpha = rg * rg;
        float a2g   = alpha * alpha;
        float den   = NdotH * NdotH * (a2g - 1.0f) + 1.0f;
        float D     = a2g / (PI_F * den * den);
        float e     = exp2f((-5.55473f * VdotH - 6.98316f) * VdotH);
        float k     = alpha * 0.5f;
        float G     = (1.0f / (NdotL * (1.0f - k) + k)) * (1.0f / (NdotV * (1.0f - k) + k));
        float sDG   = 0.25f * D * G;

        float* iv = &imgsv[p * 3];
        {
            float F0[3] = {f0x, f0y, f0z};
            float AL[3] = {a0, a1, a2c};
#pragma unroll
            for (int ch = 0; ch < 3; ++ch) {
                float F    = F0[ch] + (1.0f - F0[ch]) * e;
                float spec = sDG * F;
                float diff = AL[ch] * (1.0f - F0[ch]) * (1.0f / PI_F);
                iv[ch] = fmaxf((diff + spec) * NdotL, 0.0f);
            }
        }
    }

    // ---- stores ----
    // imgs: 6 floats per thread, 8-byte aligned -> 3x float2.
    float2* ip = reinterpret_cast<float2*>(out + (size_t)gpix * 3);
    ip[0] = make_float2(imgsv[0], imgsv[1]);
    ip[1] = make_float2(imgsv[2], imgsv[3]);
    ip[2] = make_float2(imgsv[4], imgsv[5]);

    // data: 24 floats per thread, 16-byte aligned -> 6x float4.
    float4* dp = reinterpret_cast<float4*>(out + (size_t)IMGS + (size_t)gpix * 12);
#pragma unroll
    for (int q = 0; q < 6; ++q)
        dp[q] = make_float4(datav[q * 4 + 0], datav[q * 4 + 1],
                            datav[q * 4 + 2], datav[q * 4 + 3]);
}

extern "C" void kernel_launch(void* const* d_in, const int* in_sizes, int n_in,
                              void* d_out, int out_size, void* d_ws, size_t ws_size,
                              hipStream_t stream) {
    const float* feats = (const float*)d_in[0];
    const float* wi    = (const float*)d_in[1];
    const float* wo    = (const float*)d_in[2];
    const float* wn    = (const float*)d_in[3];
    const float* wa    = (const float*)d_in[4];
    const float* wr    = (const float*)d_in[5];
    const float* wf    = (const float*)d_in[6];
    float* out = (float*)d_out;

    dim3 grid(Bc * BPI);   // 1024 blocks
    dim3 block(BLK);
    hipLaunchKernelGGL(brdf_fwd, grid, block, 0, stream,
                       feats, wi, wo, wn, wa, wr, wf, out);
}